// Round 14
// baseline (92.089 us; speedup 1.0000x reference)
//
#include <hip/hip_runtime.h>
#include <math.h>

#define NPTS 8192
#define TPB  256
#define NC_MAX 256        // padded candidate count (32 dims x 8 extremes)
#define QPB  64           // queries per fused block
#define NCH  4            // candidate chunks (waves) per fused block
#define CPC  64           // candidates per chunk

__device__ __forceinline__ float fmax3(float a, float b, float c) {
    return fmaxf(fmaxf(a, b), c);
}

// Forced v_max3_f32 with abs modifiers (R10/R11-proven bit-correct).
__device__ __forceinline__ float max3abs(float a, float b, float c) {
    float r;
    asm("v_max3_f32 %0, |%1|, |%2|, |%3|" : "=v"(r) : "v"(a), "v"(b), "v"(c));
    return r;
}
__device__ __forceinline__ float max3vaa(float m, float b, float c) {
    float r;
    asm("v_max3_f32 %0, %1, |%2|, |%3|" : "=v"(r) : "v"(m), "v"(b), "v"(c));
    return r;
}
__device__ __forceinline__ float max3v(float a, float b, float c) {
    float r;
    asm("v_max3_f32 %0, %1, %2, %3" : "=v"(r) : "v"(a), "v"(b), "v"(c));
    return r;
}

// 32-dim Chebyshev: 32 subs + 16 max3/max ops.
__device__ __forceinline__ float cheb32_pair(const float* __restrict__ q,
                                             const float* __restrict__ p) {
    float s[32];
    #pragma unroll
    for (int k = 0; k < 32; ++k) s[k] = q[k] - p[k];
    float l[10];
    #pragma unroll
    for (int g = 0; g < 10; ++g) l[g] = max3abs(s[3*g], s[3*g+1], s[3*g+2]);
    float c3 = max3vaa(l[9], s[30], s[31]);
    float c0 = max3v(l[0], l[1], l[2]);
    float c1 = max3v(l[3], l[4], l[5]);
    float c2 = max3v(l[6], l[7], l[8]);
    return fmaxf(max3v(c0, c1, c2), c3);
}

// Branchless top-4 insert, indices on levels 0-2 (R8-proven).
__device__ __forceinline__ void ins4p(float d, int di,
    float& t0, float& t1, float& t2, float& t3,
    int& i0, int& i1, int& i2)
{
    bool c0 = d > t0;
    float v1 = fminf(t0, d); int j1 = c0 ? i0 : di;
    t0 = fmaxf(t0, d);       i0 = c0 ? di : i0;
    bool c1 = v1 > t1;
    float v2 = fminf(t1, v1); int j2 = c1 ? i1 : j1;
    t1 = fmaxf(t1, v1);       i1 = c1 ? j1 : i1;
    bool c2 = v2 > t2;
    float v3 = fminf(t2, v2);
    t2 = fmaxf(t2, v2);       i2 = c2 ? j2 : i2;
    t3 = fmaxf(t3, v3);
}

// Branchless top-4 insert with indices on ALL 4 levels (for extremes).
__device__ __forceinline__ void ins4full(float d, int di,
    float& t0, float& t1, float& t2, float& t3,
    int& i0, int& i1, int& i2, int& i3)
{
    bool c0 = d > t0;
    float v1 = fminf(t0, d); int j1 = c0 ? i0 : di;
    t0 = fmaxf(t0, d);       i0 = c0 ? di : i0;
    bool c1 = v1 > t1;
    float v2 = fminf(t1, v1); int j2 = c1 ? i1 : j1;
    t1 = fmaxf(t1, v1);       i1 = c1 ? j1 : i1;
    bool c2 = v2 > t2;
    float v3 = fminf(t2, v2); int j3 = c2 ? i2 : j2;
    t2 = fmaxf(t2, v2);       i2 = c2 ? j2 : i2;
    bool c3 = v3 > t3;
    t3 = fmaxf(t3, v3);       i3 = c3 ? j3 : i3;
}

__device__ double digamma_d(double x) {
    double r = 0.0;
    while (x < 6.0) { r -= 1.0 / x; x += 1.0; }
    double f = 1.0 / (x * x);
    double t = f * (1.0/12.0 - f * (1.0/120.0 - f * (1.0/252.0 - f * (1.0/240.0 - f * (1.0/132.0)))));
    return r + log(x) - 0.5 / x - t;
}

__device__ __forceinline__ void load_query(float* qv, const float* __restrict__ x,
                                           const float* __restrict__ y, int q)
{
    const float4* qx4 = reinterpret_cast<const float4*>(x) + (size_t)q * 4;
    const float4* qy4 = reinterpret_cast<const float4*>(y) + (size_t)q * 4;
    #pragma unroll
    for (int i = 0; i < 4; ++i) {
        float4 v = qx4[i];
        qv[4*i+0] = v.x; qv[4*i+1] = v.y; qv[4*i+2] = v.z; qv[4*i+3] = v.w;
        float4 w = qy4[i];
        qv[16+4*i+0] = w.x; qv[16+4*i+1] = w.y; qv[16+4*i+2] = w.z; qv[16+4*i+3] = w.w;
    }
}

// ---------------------------------------------------------------------------
// K0: per-dim extremes, one block per dim (R13-proven ~4 us). Also zeroes acc
// (completes before the fused kernel's atomicAdds by stream order).
// THEOREM (exact, R12/R13-validated absmax 0.0): the global top-4 values and
// top-3 indices lie in the union of per-dim 4-lowest/4-highest points.
// ---------------------------------------------------------------------------
__global__ __launch_bounds__(256) void extremes_kernel(
    const float* __restrict__ x, const float* __restrict__ y,
    unsigned short* __restrict__ cand_raw, double* __restrict__ acc)
{
    const int dim  = blockIdx.x;             // 0..31
    const int tid  = threadIdx.x;
    const int lane = tid & 63;
    const int wave = tid >> 6;               // 0..3
    if (dim == 0 && tid == 0) acc[0] = 0.0;
    const float* base = (dim < 16) ? (x + dim) : (y + (dim - 16));

    float h0=-3.4e38f,h1=-3.4e38f,h2=-3.4e38f,h3=-3.4e38f;  // top-4 max
    int   a0=0,a1=0,a2=0,a3=0;
    float l0=-3.4e38f,l1=-3.4e38f,l2=-3.4e38f,l3=-3.4e38f;  // top-4 of (-v) = min
    int   b0=0,b1=0,b2=0,b3=0;
    #pragma unroll 8
    for (int j = tid; j < NPTS; j += 256) {
        float v = base[(size_t)j * 16];
        ins4full( v, j, h0,h1,h2,h3, a0,a1,a2,a3);
        ins4full(-v, j, l0,l1,l2,l3, b0,b1,b2,b3);
    }
    #pragma unroll
    for (int off = 32; off > 0; off >>= 1) {
        float m0=__shfl_xor(h0,off), m1=__shfl_xor(h1,off),
              m2=__shfl_xor(h2,off), m3=__shfl_xor(h3,off);
        int   c0=__shfl_xor(a0,off), c1=__shfl_xor(a1,off),
              c2=__shfl_xor(a2,off), c3=__shfl_xor(a3,off);
        ins4full(m0,c0, h0,h1,h2,h3, a0,a1,a2,a3);
        ins4full(m1,c1, h0,h1,h2,h3, a0,a1,a2,a3);
        ins4full(m2,c2, h0,h1,h2,h3, a0,a1,a2,a3);
        ins4full(m3,c3, h0,h1,h2,h3, a0,a1,a2,a3);
        float n0=__shfl_xor(l0,off), n1=__shfl_xor(l1,off),
              n2=__shfl_xor(l2,off), n3=__shfl_xor(l3,off);
        int   d0=__shfl_xor(b0,off), d1=__shfl_xor(b1,off),
              d2=__shfl_xor(b2,off), d3=__shfl_xor(b3,off);
        ins4full(n0,d0, l0,l1,l2,l3, b0,b1,b2,b3);
        ins4full(n1,d1, l0,l1,l2,l3, b0,b1,b2,b3);
        ins4full(n2,d2, l0,l1,l2,l3, b0,b1,b2,b3);
        ins4full(n3,d3, l0,l1,l2,l3, b0,b1,b2,b3);
    }
    __shared__ float shv[4][8];
    __shared__ int   shi[4][8];
    if (lane == 0) {
        shv[wave][0]=h0; shv[wave][1]=h1; shv[wave][2]=h2; shv[wave][3]=h3;
        shv[wave][4]=l0; shv[wave][5]=l1; shv[wave][6]=l2; shv[wave][7]=l3;
        shi[wave][0]=a0; shi[wave][1]=a1; shi[wave][2]=a2; shi[wave][3]=a3;
        shi[wave][4]=b0; shi[wave][5]=b1; shi[wave][6]=b2; shi[wave][7]=b3;
    }
    __syncthreads();
    if (tid == 0) {
        #pragma unroll
        for (int w = 1; w < 4; ++w) {
            #pragma unroll
            for (int e = 0; e < 4; ++e) {
                ins4full(shv[w][e],   shi[w][e],   h0,h1,h2,h3, a0,a1,a2,a3);
                ins4full(shv[w][4+e], shi[w][4+e], l0,l1,l2,l3, b0,b1,b2,b3);
            }
        }
        cand_raw[dim*8+0] = (unsigned short)a0;
        cand_raw[dim*8+1] = (unsigned short)a1;
        cand_raw[dim*8+2] = (unsigned short)a2;
        cand_raw[dim*8+3] = (unsigned short)a3;
        cand_raw[dim*8+4] = (unsigned short)b0;
        cand_raw[dim*8+5] = (unsigned short)b1;
        cand_raw[dim*8+6] = (unsigned short)b2;
        cand_raw[dim*8+7] = (unsigned short)b3;
    }
}

// ---------------------------------------------------------------------------
// K0b: dedupe the 256 raw candidates. LDS bitmask + compaction.
// Output: compacted prefix + 0xFFFF sentinels. (R12-proven)
// ---------------------------------------------------------------------------
__global__ __launch_bounds__(256) void dedupe_kernel(
    const unsigned short* __restrict__ cand_raw,
    unsigned short* __restrict__ dlist)
{
    __shared__ unsigned mask[NPTS / 32];
    __shared__ unsigned short tmp[NC_MAX];
    __shared__ int cnt;
    const int tid = threadIdx.x;
    mask[tid] = 0;
    if (tid == 0) cnt = 0;
    __syncthreads();
    const int idx = cand_raw[tid];
    const unsigned bit = 1u << (idx & 31);
    unsigned old = atomicOr(&mask[idx >> 5], bit);
    if (!(old & bit)) { int p = atomicAdd(&cnt, 1); tmp[p] = (unsigned short)idx; }
    __syncthreads();
    dlist[tid] = (tid < cnt) ? tmp[tid] : (unsigned short)0xFFFF;
}

// ---------------------------------------------------------------------------
// K1 (fused): candidate sweep + merge + exact 3-candidate count + digamma.
// 128 blocks x 256 threads. Each block owns QPB=64 queries; wave w scans
// candidate chunk [w*64, w*64+64) of the deduped list (staged in LDS,
// wave-uniform broadcast reads, chunk-prefix sentinel break). Wave 0 merges
// the 4 chunk partials from LDS, then runs the exact check: every point
// outside the joint top-3 has d_joint <= t3 = r, hence dx <= r and dy <= r
// bit-exactly (marginal max over a subset of the same f32 values). digamma
// + 64-lane shuffle reduce + one f64 atomicAdd per block.
// ---------------------------------------------------------------------------
__global__ __launch_bounds__(TPB) void cand_check_kernel(
    const float* __restrict__ x, const float* __restrict__ y,
    const unsigned short* __restrict__ dlist, double* __restrict__ acc)
{
    __shared__ float pc[NC_MAX * 32];            // 32 KB candidate matrix
    __shared__ unsigned short scidx[NC_MAX];
    __shared__ float4  sv[NCH][QPB];
    __shared__ ushort4 si[NCH][QPB];
    const int tid = threadIdx.x;
    const int ql  = tid & (QPB - 1);             // lane within wave = query slot
    const int ck  = tid >> 6;                    // wave id = candidate chunk
    const int q   = blockIdx.x * QPB + ql;

    scidx[tid] = dlist[tid];
    __syncthreads();
    #pragma unroll
    for (int it = 0; it < (NC_MAX * 32) / TPB; ++it) {
        int e = it * TPB + tid;
        int cand = e >> 5, dim = e & 31;
        int ci = scidx[cand];
        int j = (ci == 0xFFFF) ? 0 : ci;
        pc[e] = (dim < 16) ? x[(size_t)j * 16 + dim] : y[(size_t)j * 16 + dim - 16];
    }

    float qv[32];
    load_query(qv, x, y, q);
    float t0=-1.f,t1=-1.f,t2=-1.f,t3=-1.f;
    int i0=0,i1=0,i2=0;
    __syncthreads();

    for (int jj = ck * CPC; jj < ck * CPC + CPC; ++jj) {
        int ci = scidx[jj];                   // wave-uniform
        if (ci == 0xFFFF) break;              // compacted: prefix holds per chunk
        float m = cheb32_pair(qv, pc + jj * 32);
        ins4p(m, ci, t0, t1, t2, t3, i0, i1, i2);
    }
    sv[ck][ql] = make_float4(t0, t1, t2, t3);
    si[ck][ql] = make_ushort4((unsigned short)i0, (unsigned short)i1,
                              (unsigned short)i2, 0);
    __syncthreads();

    if (ck == 0) {
        #pragma unroll
        for (int c = 1; c < NCH; ++c) {
            float4  v  = sv[c][ql];
            ushort4 id = si[c][ql];
            ins4p(v.x, id.x, t0,t1,t2,t3, i0,i1,i2);
            ins4p(v.y, id.y, t0,t1,t2,t3, i0,i1,i2);
            ins4p(v.z, id.z, t0,t1,t2,t3, i0,i1,i2);
            ins4p(v.w, 0,    t0,t1,t2,t3, i0,i1,i2);  // 4th: value-only (safe)
        }
        const float rq = t3 - 1e-15f;  // == t3 bit-exact in f32 (reference fidelity)

        float vals[3] = { t0, t1, t2 };
        int   idxs[3] = { i0, i1, i2 };
        int missx = 0, missy = 0;
        #pragma unroll
        for (int k = 0; k < 3; ++k) {
            const int j = idxs[k];
            const float4* px4 = reinterpret_cast<const float4*>(x) + (size_t)j * 4;
            const float4* py4 = reinterpret_cast<const float4*>(y) + (size_t)j * 4;
            float mx = 0.0f, my = 0.0f;
            #pragma unroll
            for (int i = 0; i < 4; ++i) {
                float4 a = px4[i];
                mx = fmax3(mx, fmax3(fabsf(qv[4*i+0]-a.x), fabsf(qv[4*i+1]-a.y),
                                     fabsf(qv[4*i+2]-a.z)), fabsf(qv[4*i+3]-a.w));
                float4 b = py4[i];
                my = fmax3(my, fmax3(fabsf(qv[16+4*i+0]-b.x), fabsf(qv[16+4*i+1]-b.y),
                                     fabsf(qv[16+4*i+2]-b.z)), fabsf(qv[16+4*i+3]-b.w));
            }
            const bool act = vals[k] > rq;   // only strict-greater joints can miss
            missx += (act && (mx > rq)) ? 1 : 0;
            missy += (act && (my > rq)) ? 1 : 0;
        }
        const int nx = NPTS - missx;
        const int ny = NPTS - missy;
        double d = digamma_d((double)nx) + digamma_d((double)ny);
        #pragma unroll
        for (int off = 32; off > 0; off >>= 1)
            d += __shfl_down(d, off, 64);
        if (ql == 0) atomicAdd(acc, d);
    }
}

// ---------------------------------------------------------------------------
// K2: ans = psi(N) + psi(k) - acc/N  (log terms cancel exactly)
// ---------------------------------------------------------------------------
__global__ __launch_bounds__(64) void final_kernel(
    const double* __restrict__ acc, float* __restrict__ out)
{
    if (threadIdx.x == 0) {
        double ans = digamma_d((double)NPTS) + digamma_d(4.0) - acc[0] / (double)NPTS;
        out[0] = (float)ans;
    }
}

// ---------------------------------------------------------------------------
extern "C" void kernel_launch(void* const* d_in, const int* in_sizes, int n_in,
                              void* d_out, int out_size, void* d_ws, size_t ws_size,
                              hipStream_t stream)
{
    (void)in_sizes; (void)n_in; (void)out_size; (void)ws_size;
    const float* x = (const float*)d_in[0];
    const float* y = (const float*)d_in[1];
    float* out = (float*)d_out;

    // workspace: acc f64 @0 (16B) | cand_raw 256 u16 @16 | dlist 256 u16 @528
    char* ws = (char*)d_ws;
    double* acc = (double*)ws;
    unsigned short* cand_raw = (unsigned short*)(ws + 16);
    unsigned short* dlist    = (unsigned short*)(ws + 528);

    extremes_kernel<<<32, 256, 0, stream>>>(x, y, cand_raw, acc);
    dedupe_kernel<<<1, 256, 0, stream>>>(cand_raw, dlist);
    cand_check_kernel<<<NPTS / QPB, TPB, 0, stream>>>(x, y, dlist, acc);
    final_kernel<<<1, 64, 0, stream>>>(acc, out);
}

// Round 15
// 91.095 us; speedup vs baseline: 1.0109x; 1.0109x over previous
//
#include <hip/hip_runtime.h>
#include <math.h>

#define NPTS 8192
#define TPB  256
#define NC_MAX 256        // padded candidate count (32 dims x 8 extremes)
#define QPB  64           // queries per fused block
#define NCH  4            // candidate chunks (waves) per fused block
#define CPC  64           // candidates per chunk
#define NBLK (NPTS / QPB) // 128 fused blocks

__device__ __forceinline__ float fmax3(float a, float b, float c) {
    return fmaxf(fmaxf(a, b), c);
}

// Forced v_max3_f32 with abs modifiers (R10/R11-proven bit-correct).
__device__ __forceinline__ float max3abs(float a, float b, float c) {
    float r;
    asm("v_max3_f32 %0, |%1|, |%2|, |%3|" : "=v"(r) : "v"(a), "v"(b), "v"(c));
    return r;
}
__device__ __forceinline__ float max3vaa(float m, float b, float c) {
    float r;
    asm("v_max3_f32 %0, %1, |%2|, |%3|" : "=v"(r) : "v"(m), "v"(b), "v"(c));
    return r;
}
__device__ __forceinline__ float max3v(float a, float b, float c) {
    float r;
    asm("v_max3_f32 %0, %1, %2, %3" : "=v"(r) : "v"(a), "v"(b), "v"(c));
    return r;
}

// 32-dim Chebyshev: 32 subs + 16 max3/max ops.
__device__ __forceinline__ float cheb32_pair(const float* __restrict__ q,
                                             const float* __restrict__ p) {
    float s[32];
    #pragma unroll
    for (int k = 0; k < 32; ++k) s[k] = q[k] - p[k];
    float l[10];
    #pragma unroll
    for (int g = 0; g < 10; ++g) l[g] = max3abs(s[3*g], s[3*g+1], s[3*g+2]);
    float c3 = max3vaa(l[9], s[30], s[31]);
    float c0 = max3v(l[0], l[1], l[2]);
    float c1 = max3v(l[3], l[4], l[5]);
    float c2 = max3v(l[6], l[7], l[8]);
    return fmaxf(max3v(c0, c1, c2), c3);
}

// Branchless top-4 insert, indices on levels 0-2 (R8-proven).
__device__ __forceinline__ void ins4p(float d, int di,
    float& t0, float& t1, float& t2, float& t3,
    int& i0, int& i1, int& i2)
{
    bool c0 = d > t0;
    float v1 = fminf(t0, d); int j1 = c0 ? i0 : di;
    t0 = fmaxf(t0, d);       i0 = c0 ? di : i0;
    bool c1 = v1 > t1;
    float v2 = fminf(t1, v1); int j2 = c1 ? i1 : j1;
    t1 = fmaxf(t1, v1);       i1 = c1 ? j1 : i1;
    bool c2 = v2 > t2;
    float v3 = fminf(t2, v2);
    t2 = fmaxf(t2, v2);       i2 = c2 ? j2 : i2;
    t3 = fmaxf(t3, v3);
}

// Branchless top-4 insert with indices on ALL 4 levels (for extremes).
__device__ __forceinline__ void ins4full(float d, int di,
    float& t0, float& t1, float& t2, float& t3,
    int& i0, int& i1, int& i2, int& i3)
{
    bool c0 = d > t0;
    float v1 = fminf(t0, d); int j1 = c0 ? i0 : di;
    t0 = fmaxf(t0, d);       i0 = c0 ? di : i0;
    bool c1 = v1 > t1;
    float v2 = fminf(t1, v1); int j2 = c1 ? i1 : j1;
    t1 = fmaxf(t1, v1);       i1 = c1 ? j1 : i1;
    bool c2 = v2 > t2;
    float v3 = fminf(t2, v2); int j3 = c2 ? i2 : j2;
    t2 = fmaxf(t2, v2);       i2 = c2 ? j2 : i2;
    bool c3 = v3 > t3;
    t3 = fmaxf(t3, v3);       i3 = c3 ? j3 : i3;
}

__device__ double digamma_d(double x) {
    double r = 0.0;
    while (x < 6.0) { r -= 1.0 / x; x += 1.0; }
    double f = 1.0 / (x * x);
    double t = f * (1.0/12.0 - f * (1.0/120.0 - f * (1.0/252.0 - f * (1.0/240.0 - f * (1.0/132.0)))));
    return r + log(x) - 0.5 / x - t;
}

__device__ __forceinline__ void load_query(float* qv, const float* __restrict__ x,
                                           const float* __restrict__ y, int q)
{
    const float4* qx4 = reinterpret_cast<const float4*>(x) + (size_t)q * 4;
    const float4* qy4 = reinterpret_cast<const float4*>(y) + (size_t)q * 4;
    #pragma unroll
    for (int i = 0; i < 4; ++i) {
        float4 v = qx4[i];
        qv[4*i+0] = v.x; qv[4*i+1] = v.y; qv[4*i+2] = v.z; qv[4*i+3] = v.w;
        float4 w = qy4[i];
        qv[16+4*i+0] = w.x; qv[16+4*i+1] = w.y; qv[16+4*i+2] = w.z; qv[16+4*i+3] = w.w;
    }
}

// ---------------------------------------------------------------------------
// K0: per-dim extremes, one block per dim (R13-proven ~4 us). Also zeroes
// acc and the ticket counter (stream order guarantees visibility to K1).
// THEOREM (exact, R12/R13/R14-validated absmax 0.0): the global top-4 values
// and top-3 indices lie in the union of per-dim 4-lowest/4-highest points.
// ---------------------------------------------------------------------------
__global__ __launch_bounds__(256) void extremes_kernel(
    const float* __restrict__ x, const float* __restrict__ y,
    unsigned short* __restrict__ cand_raw, double* __restrict__ acc,
    unsigned* __restrict__ done)
{
    const int dim  = blockIdx.x;             // 0..31
    const int tid  = threadIdx.x;
    const int lane = tid & 63;
    const int wave = tid >> 6;               // 0..3
    if (dim == 0 && tid == 0) { acc[0] = 0.0; done[0] = 0u; }
    const float* base = (dim < 16) ? (x + dim) : (y + (dim - 16));

    float h0=-3.4e38f,h1=-3.4e38f,h2=-3.4e38f,h3=-3.4e38f;  // top-4 max
    int   a0=0,a1=0,a2=0,a3=0;
    float l0=-3.4e38f,l1=-3.4e38f,l2=-3.4e38f,l3=-3.4e38f;  // top-4 of (-v) = min
    int   b0=0,b1=0,b2=0,b3=0;
    #pragma unroll 8
    for (int j = tid; j < NPTS; j += 256) {
        float v = base[(size_t)j * 16];
        ins4full( v, j, h0,h1,h2,h3, a0,a1,a2,a3);
        ins4full(-v, j, l0,l1,l2,l3, b0,b1,b2,b3);
    }
    #pragma unroll
    for (int off = 32; off > 0; off >>= 1) {
        float m0=__shfl_xor(h0,off), m1=__shfl_xor(h1,off),
              m2=__shfl_xor(h2,off), m3=__shfl_xor(h3,off);
        int   c0=__shfl_xor(a0,off), c1=__shfl_xor(a1,off),
              c2=__shfl_xor(a2,off), c3=__shfl_xor(a3,off);
        ins4full(m0,c0, h0,h1,h2,h3, a0,a1,a2,a3);
        ins4full(m1,c1, h0,h1,h2,h3, a0,a1,a2,a3);
        ins4full(m2,c2, h0,h1,h2,h3, a0,a1,a2,a3);
        ins4full(m3,c3, h0,h1,h2,h3, a0,a1,a2,a3);
        float n0=__shfl_xor(l0,off), n1=__shfl_xor(l1,off),
              n2=__shfl_xor(l2,off), n3=__shfl_xor(l3,off);
        int   d0=__shfl_xor(b0,off), d1=__shfl_xor(b1,off),
              d2=__shfl_xor(b2,off), d3=__shfl_xor(b3,off);
        ins4full(n0,d0, l0,l1,l2,l3, b0,b1,b2,b3);
        ins4full(n1,d1, l0,l1,l2,l3, b0,b1,b2,b3);
        ins4full(n2,d2, l0,l1,l2,l3, b0,b1,b2,b3);
        ins4full(n3,d3, l0,l1,l2,l3, b0,b1,b2,b3);
    }
    __shared__ float shv[4][8];
    __shared__ int   shi[4][8];
    if (lane == 0) {
        shv[wave][0]=h0; shv[wave][1]=h1; shv[wave][2]=h2; shv[wave][3]=h3;
        shv[wave][4]=l0; shv[wave][5]=l1; shv[wave][6]=l2; shv[wave][7]=l3;
        shi[wave][0]=a0; shi[wave][1]=a1; shi[wave][2]=a2; shi[wave][3]=a3;
        shi[wave][4]=b0; shi[wave][5]=b1; shi[wave][6]=b2; shi[wave][7]=b3;
    }
    __syncthreads();
    if (tid == 0) {
        #pragma unroll
        for (int w = 1; w < 4; ++w) {
            #pragma unroll
            for (int e = 0; e < 4; ++e) {
                ins4full(shv[w][e],   shi[w][e],   h0,h1,h2,h3, a0,a1,a2,a3);
                ins4full(shv[w][4+e], shi[w][4+e], l0,l1,l2,l3, b0,b1,b2,b3);
            }
        }
        cand_raw[dim*8+0] = (unsigned short)a0;
        cand_raw[dim*8+1] = (unsigned short)a1;
        cand_raw[dim*8+2] = (unsigned short)a2;
        cand_raw[dim*8+3] = (unsigned short)a3;
        cand_raw[dim*8+4] = (unsigned short)b0;
        cand_raw[dim*8+5] = (unsigned short)b1;
        cand_raw[dim*8+6] = (unsigned short)b2;
        cand_raw[dim*8+7] = (unsigned short)b3;
    }
}

// ---------------------------------------------------------------------------
// K1 (fully fused): per-block dedupe + candidate sweep + merge + exact
// 3-candidate count + digamma + grid reduction + final answer.
// 128 blocks x 256 threads; block owns QPB=64 queries, wave w scans candidate
// chunk w (wave-uniform LDS broadcast, prefix-sentinel break). Wave 0 merges
// chunk partials, runs the exact check (every point outside the joint top-3
// has d_joint <= t3 = r, hence dx <= r and dy <= r bit-exactly), digamma,
// 64-lane shuffle reduce, one f64 atomicAdd. Fence+ticket: the last block
// re-reads acc coherently (atomicAdd(acc,0.0)) and writes the answer --
// device-scope atomics are XCD-safe (G12/G16).
// ---------------------------------------------------------------------------
__global__ __launch_bounds__(TPB) void cand_check_kernel(
    const float* __restrict__ x, const float* __restrict__ y,
    const unsigned short* __restrict__ cand_raw, double* __restrict__ acc,
    unsigned* __restrict__ done, float* __restrict__ out)
{
    __shared__ float pc[NC_MAX * 32];            // 32 KB candidate matrix
    __shared__ unsigned short scidx[NC_MAX];
    __shared__ unsigned mask[NPTS / 32];         // 1 KB dedupe bitmask
    __shared__ unsigned short tmp[NC_MAX];
    __shared__ int cnt;
    __shared__ float4  sv[NCH][QPB];
    __shared__ ushort4 si[NCH][QPB];
    const int tid = threadIdx.x;
    const int ql  = tid & (QPB - 1);             // query slot within wave
    const int ck  = tid >> 6;                    // wave id = candidate chunk
    const int q   = blockIdx.x * QPB + ql;

    // --- inline dedupe (R12-proven logic, replicated per block) ---
    mask[tid] = 0;
    if (tid == 0) cnt = 0;
    __syncthreads();
    {
        const int idx = cand_raw[tid];
        const unsigned bit = 1u << (idx & 31);
        unsigned old = atomicOr(&mask[idx >> 5], bit);
        if (!(old & bit)) { int p = atomicAdd(&cnt, 1); tmp[p] = (unsigned short)idx; }
    }
    __syncthreads();
    scidx[tid] = (tid < cnt) ? tmp[tid] : (unsigned short)0xFFFF;
    __syncthreads();

    // --- stage candidate matrix ---
    #pragma unroll
    for (int it = 0; it < (NC_MAX * 32) / TPB; ++it) {
        int e = it * TPB + tid;
        int cand = e >> 5, dim = e & 31;
        int ci = scidx[cand];
        int j = (ci == 0xFFFF) ? 0 : ci;
        pc[e] = (dim < 16) ? x[(size_t)j * 16 + dim] : y[(size_t)j * 16 + dim - 16];
    }

    float qv[32];
    load_query(qv, x, y, q);
    float t0=-1.f,t1=-1.f,t2=-1.f,t3=-1.f;
    int i0=0,i1=0,i2=0;
    __syncthreads();

    for (int jj = ck * CPC; jj < ck * CPC + CPC; ++jj) {
        int ci = scidx[jj];                   // wave-uniform
        if (ci == 0xFFFF) break;              // compacted: prefix holds per chunk
        float m = cheb32_pair(qv, pc + jj * 32);
        ins4p(m, ci, t0, t1, t2, t3, i0, i1, i2);
    }
    sv[ck][ql] = make_float4(t0, t1, t2, t3);
    si[ck][ql] = make_ushort4((unsigned short)i0, (unsigned short)i1,
                              (unsigned short)i2, 0);
    __syncthreads();

    if (ck == 0) {
        #pragma unroll
        for (int c = 1; c < NCH; ++c) {
            float4  v  = sv[c][ql];
            ushort4 id = si[c][ql];
            ins4p(v.x, id.x, t0,t1,t2,t3, i0,i1,i2);
            ins4p(v.y, id.y, t0,t1,t2,t3, i0,i1,i2);
            ins4p(v.z, id.z, t0,t1,t2,t3, i0,i1,i2);
            ins4p(v.w, 0,    t0,t1,t2,t3, i0,i1,i2);  // 4th: value-only (safe)
        }
        const float rq = t3 - 1e-15f;  // == t3 bit-exact in f32 (reference fidelity)

        float vals[3] = { t0, t1, t2 };
        int   idxs[3] = { i0, i1, i2 };
        int missx = 0, missy = 0;
        #pragma unroll
        for (int k = 0; k < 3; ++k) {
            const int j = idxs[k];
            const float4* px4 = reinterpret_cast<const float4*>(x) + (size_t)j * 4;
            const float4* py4 = reinterpret_cast<const float4*>(y) + (size_t)j * 4;
            float mx = 0.0f, my = 0.0f;
            #pragma unroll
            for (int i = 0; i < 4; ++i) {
                float4 a = px4[i];
                mx = fmax3(mx, fmax3(fabsf(qv[4*i+0]-a.x), fabsf(qv[4*i+1]-a.y),
                                     fabsf(qv[4*i+2]-a.z)), fabsf(qv[4*i+3]-a.w));
                float4 b = py4[i];
                my = fmax3(my, fmax3(fabsf(qv[16+4*i+0]-b.x), fabsf(qv[16+4*i+1]-b.y),
                                     fabsf(qv[16+4*i+2]-b.z)), fabsf(qv[16+4*i+3]-b.w));
            }
            const bool act = vals[k] > rq;   // only strict-greater joints can miss
            missx += (act && (mx > rq)) ? 1 : 0;
            missy += (act && (my > rq)) ? 1 : 0;
        }
        const int nx = NPTS - missx;
        const int ny = NPTS - missy;
        double d = digamma_d((double)nx) + digamma_d((double)ny);
        #pragma unroll
        for (int off = 32; off > 0; off >>= 1)
            d += __shfl_down(d, off, 64);
        if (ql == 0) {
            atomicAdd(acc, d);
            __threadfence();                       // add visible before ticket
            unsigned ticket = atomicAdd(done, 1u);
            if (ticket == NBLK - 1) {              // last block: finalize
                double s = atomicAdd(acc, 0.0);    // coherent device-scope read
                double ans = digamma_d((double)NPTS) + digamma_d(4.0)
                           - s / (double)NPTS;
                out[0] = (float)ans;
            }
        }
    }
}

// ---------------------------------------------------------------------------
extern "C" void kernel_launch(void* const* d_in, const int* in_sizes, int n_in,
                              void* d_out, int out_size, void* d_ws, size_t ws_size,
                              hipStream_t stream)
{
    (void)in_sizes; (void)n_in; (void)out_size; (void)ws_size;
    const float* x = (const float*)d_in[0];
    const float* y = (const float*)d_in[1];
    float* out = (float*)d_out;

    // workspace: acc f64 @0 | done u32 @8 | cand_raw 256 u16 @16
    char* ws = (char*)d_ws;
    double*   acc      = (double*)ws;
    unsigned* done     = (unsigned*)(ws + 8);
    unsigned short* cand_raw = (unsigned short*)(ws + 16);

    extremes_kernel<<<32, 256, 0, stream>>>(x, y, cand_raw, acc, done);
    cand_check_kernel<<<NBLK, TPB, 0, stream>>>(x, y, cand_raw, acc, done, out);
}